// Round 12
// baseline (187.946 us; speedup 1.0000x reference)
//
#include <hip/hip_runtime.h>
#include <hip/hip_fp16.h>

#define NQ     14
#define NL     4
#define BATCH  2048
#define DIM    16384
#define BLK    512
#define NCH    (DIM / 4)            // 4096 logical uint4 chunks (4 amps, fp16 SoA)
#define PCH    (NCH + NCH / 16)     // 4352 physical chunks (pad c + c>>4: bank-clean)

using f2 = __attribute__((ext_vector_type(2))) float;
__device__ __forceinline__ f2 ff2(float a, float b) { f2 r; r.x = a; r.y = b; return r; }

__device__ __forceinline__ unsigned h2u(__half2 h) { return __builtin_bit_cast(unsigned, h); }
__device__ __forceinline__ __half2 u2h(unsigned u) { return __builtin_bit_cast(__half2, u); }
__device__ __forceinline__ unsigned sw16(unsigned u) { return __builtin_amdgcn_alignbit(u, u, 16); }

// ---- Shear RX in packed fp16 (3 pk-FMA per 2D plane pair; swap-free for amp-bit>=1).
// X[k]=(x_{2k},x_{2k+1}), Y[k]=(y_{2k},y_{2k+1}).  T=(t,t), Sn=(-s,-s),
// t = tan(phi/2) rounded to fp16, s derived from rounded t (map stays a rotation).
template <int K>  // K = amp-bit >> 1, for amp-bit >= 1
__device__ __forceinline__ void rot_k(__half2* X, __half2* Y, __half2 T, __half2 Sn) {
#pragma unroll
  for (int k = 0; k < 16; ++k) {
    if (!(k & K)) {
      const int k1 = k | K;
      const __half2 u1 = __hfma2(T, Y[k1], X[k]);
      const __half2 w1 = __hfma2(Sn, u1, Y[k1]);
      X[k]  = __hfma2(T, w1, u1);
      Y[k1] = w1;
      const __half2 u2 = __hfma2(T, Y[k], X[k1]);
      const __half2 w2 = __hfma2(Sn, u2, Y[k]);
      X[k1] = __hfma2(T, w2, u2);
      Y[k]  = w2;
    }
  }
}
// amp-bit 0 (q13): partner inside the packed register -> half-swaps
__device__ __forceinline__ void rot0(__half2* X, __half2* Y, __half2 T, __half2 Sn) {
#pragma unroll
  for (int k = 0; k < 16; ++k) {
    const __half2 sy = __lowhigh2highlow(Y[k]);
    const __half2 u = __hfma2(T, sy, X[k]);
    const __half2 w = __hfma2(Sn, u, sy);
    X[k] = __hfma2(T, w, u);
    Y[k] = __lowhigh2highlow(w);
  }
}

__global__ __launch_bounds__(BLK)
__attribute__((amdgpu_waves_per_eu(4, 4)))   // VGPR cap 128; exactly 2 blocks/CU
void qsim_kernel(const float* __restrict__ x,
                 const float* __restrict__ params,
                 float* __restrict__ out) {
  __shared__ uint4 lds[PCH];                  // 69632 B state, fp16 SoA chunks, padded
  __shared__ float exc[NQ], exs[NQ];
  __shared__ uint2 gTS[NL * NQ];              // per-gate packed (T=(t,t), Sn=(-s,-s))
  __shared__ float red[8][16];
  char* const sb = (char*)lds;

  const int b = blockIdx.x;
  const int t = threadIdx.x;

  if (t < NQ) { const float xv = x[b * NQ + t]; exc[t] = cosf(0.5f * xv); exs[t] = sinf(0.5f * xv); }
  if (t < NL * NQ) {
    float ph = 0.5f * params[t];              // phi in [0, pi]
    if (ph > 1.5707964f) ph -= 3.14159265f;   // range-reduce; global -1 is pure phase
    const float tf = tanf(0.5f * ph);
    const __half th = __float2half_rn(tf);
    const float thf = __half2float(th);
    const float sf = 2.0f * thf / (1.0f + thf * thf);  // consistent with rounded t
    gTS[t] = make_uint2(h2u(__half2half2(th)), h2u(__float2half2_rn(-sf)));
  }
  __syncthreads();

  __half2 X[16], Y[16];                       // 32 amps: SoA x/y planes, fp16 packed

  // ---- per-thread bases, pad function phys = c + (c>>4) (all banks 2-way max)
  // A: chunks c = 8t+i      -> phys = 8t + (t>>1) + i
  char* const pA = sb + 16 * (8 * t + (t >> 1));
  // B: c = (t&7)+8m+64(t>>3) -> phys = (t&7) + 68(t>>3) + [8m + (m>>1)]
  char* const pB = sb + 16 * ((t & 7) + 68 * (t >> 3));
  // C: c = (t&63)+64m+512(t>>6) -> phys = (t&63) + ((t>>4)&3) + 544(t>>6) + 68m
  char* const pC = sb + 16 * ((t & 63) + ((t >> 4) & 3) + 544 * (t >> 6));
  // D: c = t+512m            -> phys = t + (t>>4) + 544m
  char* const pD = sb + 16 * (t + (t >> 4));

  // D CNOT-fold target chunks: MA0 = image of amp bits 2..10 (=t) under ring map
  int MA0 = 0;
  {
    const int Me[9] = {0x2007, 0x200F, 0x201F, 0x203F, 0x207F, 0x20FF, 0x21FF, 0x23FF, 0x27FF};
#pragma unroll
    for (int i = 0; i < 9; ++i) if ((t >> i) & 1) MA0 ^= Me[i];
  }
  int offD[8];
#pragma unroll
  for (int g = 0; g < 8; ++g) {
    const int Mrep = ((g & 1) ? 0x2FFF : 0) ^ ((g & 2) ? 0x3FFF : 0) ^ ((g & 4) ? 0x1FFF : 0);
    const int cT = (MA0 ^ Mrep) >> 2;
    offD[g] = 16 * (cT + (cT >> 4));
  }
  const int P = __popc(t) & 1;

  // ---- embedding in pass-A ownership: amp a = 32t + 4i + l (fp32, packed once)
  {
    float pb = 1.0f;
#pragma unroll
    for (int p = 0; p < 9; ++p) pb *= ((t >> p) & 1) ? exs[8 - p] : exc[8 - p];
    const int pct = __popc(t);
#pragma unroll
    for (int i = 0; i < 8; ++i) {
      const float fc = ((i & 1) ? exs[11] : exc[11]) * ((i & 2) ? exs[10] : exc[10]) *
                       ((i & 4) ? exs[9] : exc[9]);
      float xv[4], yv[4];
#pragma unroll
      for (int l = 0; l < 4; ++l) {
        const float fl = ((l & 1) ? exs[13] : exc[13]) * ((l & 2) ? exs[12] : exc[12]);
        const float f = pb * fc * fl;
        const int pc = (pct + __popc(i) + __popc(l)) & 3;
        xv[l] = (pc == 0) ? f : ((pc == 2) ? -f : 0.0f);
        yv[l] = (pc == 1) ? -f : ((pc == 3) ? f : 0.0f);
      }
      X[2 * i]     = __floats2half2_rn(xv[0], xv[1]);
      X[2 * i + 1] = __floats2half2_rn(xv[2], xv[3]);
      Y[2 * i]     = __floats2half2_rn(yv[0], yv[1]);
      Y[2 * i + 1] = __floats2half2_rn(yv[2], yv[3]);
    }
  }

#pragma unroll
  for (int layer = 0; layer < NL; ++layer) {
    __half2 T, Sn;
#define MKST(qi) { const uint2 g_ = gTS[layer * NQ + (qi)]; T = u2h(g_.x); Sn = u2h(g_.y); }

    // ---- pass A: amps 32t+j; rotate q13..q9 (amp bits 0..4)
    if (layer > 0) {
#pragma unroll
      for (int i = 0; i < 8; ++i) {
        const uint4 u = *(const uint4*)(pA + 16 * i);
        X[2 * i] = u2h(u.x); Y[2 * i] = u2h(u.y);
        X[2 * i + 1] = u2h(u.z); Y[2 * i + 1] = u2h(u.w);
      }
    }
    MKST(13); rot0(X, Y, T, Sn);
    MKST(12); rot_k<1>(X, Y, T, Sn);
    MKST(11); rot_k<2>(X, Y, T, Sn);
    MKST(10); rot_k<4>(X, Y, T, Sn);
    MKST(9);  rot_k<8>(X, Y, T, Sn);
#pragma unroll
    for (int i = 0; i < 8; ++i)
      *(uint4*)(pA + 16 * i) = make_uint4(h2u(X[2 * i]), h2u(Y[2 * i]),
                                          h2u(X[2 * i + 1]), h2u(Y[2 * i + 1]));
    __builtin_amdgcn_wave_barrier();          // A->B exchange is wave-private

    // ---- pass B: free {0,1,5,6,7}; rotate q8,q7,q6
#pragma unroll
    for (int m = 0; m < 8; ++m) {
      const uint4 u = *(const uint4*)(pB + 16 * (8 * m + (m >> 1)));
      X[2 * m] = u2h(u.x); Y[2 * m] = u2h(u.y);
      X[2 * m + 1] = u2h(u.z); Y[2 * m + 1] = u2h(u.w);
    }
    MKST(8); rot_k<2>(X, Y, T, Sn);
    MKST(7); rot_k<4>(X, Y, T, Sn);
    MKST(6); rot_k<8>(X, Y, T, Sn);
#pragma unroll
    for (int m = 0; m < 8; ++m)
      *(uint4*)(pB + 16 * (8 * m + (m >> 1))) =
          make_uint4(h2u(X[2 * m]), h2u(Y[2 * m]),
                     h2u(X[2 * m + 1]), h2u(Y[2 * m + 1]));
    __builtin_amdgcn_wave_barrier();          // B->C exchange is wave-private

    // ---- pass C: free {0,1,8,9,10}; rotate q5,q4,q3
#pragma unroll
    for (int m = 0; m < 8; ++m) {
      const uint4 u = *(const uint4*)(pC + 1088 * m);
      X[2 * m] = u2h(u.x); Y[2 * m] = u2h(u.y);
      X[2 * m + 1] = u2h(u.z); Y[2 * m + 1] = u2h(u.w);
    }
    MKST(5); rot_k<2>(X, Y, T, Sn);
    MKST(4); rot_k<4>(X, Y, T, Sn);
    MKST(3); rot_k<8>(X, Y, T, Sn);
#pragma unroll
    for (int m = 0; m < 8; ++m)
      *(uint4*)(pC + 1088 * m) = make_uint4(h2u(X[2 * m]), h2u(Y[2 * m]),
                                            h2u(X[2 * m + 1]), h2u(Y[2 * m + 1]));
    __syncthreads();                          // C->D repartition crosses waves

    // ---- pass D: free {0,1,11,12,13}; rotate q2,q1,q0
#pragma unroll
    for (int m = 0; m < 8; ++m) {
      const uint4 u = *(const uint4*)(pD + 8704 * m);
      X[2 * m] = u2h(u.x); Y[2 * m] = u2h(u.y);
      X[2 * m + 1] = u2h(u.z); Y[2 * m + 1] = u2h(u.w);
    }
    if (layer < NL - 1) __syncthreads();      // WAR: all D reads done before CNOT writes
    MKST(2); rot_k<2>(X, Y, T, Sn);
    MKST(1); rot_k<4>(X, Y, T, Sn);
    MKST(0); rot_k<8>(X, Y, T, Sn);
#undef MKST

    if (layer < NL - 1) {
      // CNOT ring folded into full-chunk writes; half-mixes are single v_perm_b32.
#pragma unroll
      for (int g = 0; g < 8; ++g) {
        const int k0 = 2 * g;
        const unsigned w0 = __builtin_amdgcn_perm(h2u(X[k0 ^ 12]), h2u(X[k0]), 0x07060100u);
        const unsigned w1 = __builtin_amdgcn_perm(h2u(Y[k0 ^ 12]), h2u(Y[k0]), 0x07060100u);
        const unsigned w2 = __builtin_amdgcn_perm(h2u(X[k0 ^ 13]), h2u(X[k0 ^ 1]), 0x05040302u);
        const unsigned w3 = __builtin_amdgcn_perm(h2u(Y[k0 ^ 13]), h2u(Y[k0 ^ 1]), 0x05040302u);
        const bool rev = ((P ^ (__popc(g) & 1)) != 0);
        const uint4 o = make_uint4(rev ? sw16(w2) : w0, rev ? sw16(w3) : w1,
                                   rev ? sw16(w0) : w2, rev ? sw16(w1) : w3);
        *(uint4*)(sb + offD[g]) = o;
      }
      __syncthreads();                        // RAW for next layer's pass-A read
    }
  }

  // ---- measurement (final CNOT folded via GF(2) linearity); probs in fp32.
  {
    f2 pp[16];
#pragma unroll
    for (int k = 0; k < 16; ++k) {
      const float xl = __low2float(X[k]), xh = __high2float(X[k]);
      const float yl = __low2float(Y[k]), yh = __high2float(Y[k]);
      pp[k] = ff2(fmaf(xl, xl, yl * yl), fmaf(xh, xh, yh * yh));
    }
#pragma unroll
    for (int st = 0; st < 4; ++st) {
      const int h = 1 << st;
#pragma unroll
      for (int k = 0; k < 16; ++k) {
        if (!(k & h)) {
          const f2 u = pp[k], w = pp[k | h];
          pp[k] = u + w;
          pp[k | h] = u - w;
        }
      }
    }
    float w24 = pp[12].x + pp[12].y;
    float w28 = pp[14].x + pp[14].y;
    float w30 = pp[15].x + pp[15].y;
    float w31 = pp[15].x - pp[15].y;
    float w15 = pp[7].x - pp[7].y;

    const int lane = t & 63;
#pragma unroll
    for (int m = 0; m < 6; ++m) {
      const int h = 1 << m;
      const bool hi = (lane & h) != 0;
      float u;
      u = __shfl_xor(w28, h, 64); w28 = hi ? (u - w28) : (u + w28);
      u = __shfl_xor(w30, h, 64); w30 = hi ? (u - w30) : (u + w30);
      u = __shfl_xor(w31, h, 64); w31 = hi ? (u - w31) : (u + w31);
      u = __shfl_xor(w15, h, 64); w15 = hi ? (u - w15) : (u + w15);
      u = __shfl_xor(w24, h, 64); w24 = u + w24;     // plain sum: only lane 0 used
    }
    const int w = t >> 6;
    const float swv = (__popc(w) & 1) ? -1.0f : 1.0f;
    if (lane == 0) {
      red[w][1] = w24;                                   // q1: +
      red[w][2] = w28;                                   // q2: +
      red[w][3] = ((w >> 2) & 1) ? -w28 : w28;           // q3: (-1)^t10
      red[w][4] = (((w >> 1) ^ (w >> 2)) & 1) ? -w28 : w28;  // q4: t9^t10
      red[w][5] = swv * w28;                             // q5: t8^t9^t10
    } else if (lane == 32) { red[w][6]  = swv * w28; }   // q6:  lane mask 0x20
    else if (lane == 48)   { red[w][7]  = swv * w28; }   // q7:  0x30
    else if (lane == 56)   { red[w][8]  = swv * w28; }   // q8:  0x38
    else if (lane == 60)   { red[w][9]  = swv * w28; }   // q9:  0x3C
    else if (lane == 62)   { red[w][10] = swv * w28; }   // q10: 0x3E
    else if (lane == 63)   { red[w][11] = swv * w28;     // q11: 0x3F
                             red[w][12] = swv * w30;     // q12
                             red[w][13] = swv * w31;     // q13
                             red[w][0]  = swv * w15; }   // q0
    __syncthreads();
    if (t < NQ) {
      float sq = 0.0f;
#pragma unroll
      for (int ww = 0; ww < 8; ++ww) sq += red[ww][t];
      out[b * NQ + t] = sq;
    }
  }
}

extern "C" void kernel_launch(void* const* d_in, const int* in_sizes, int n_in,
                              void* d_out, int out_size, void* d_ws, size_t ws_size,
                              hipStream_t stream) {
  const float* x      = (const float*)d_in[0];
  const float* params = (const float*)d_in[1];
  float* out          = (float*)d_out;
  qsim_kernel<<<BATCH, BLK, 0, stream>>>(x, params, out);
}

// Round 13
// 162.965 us; speedup vs baseline: 1.1533x; 1.1533x over previous
//
#include <hip/hip_runtime.h>
#include <hip/hip_fp16.h>

#define NQ     14
#define NL     4
#define BATCH  2048
#define DIM    16384
#define BLK    512
#define NCH    (DIM / 4)            // 4096 logical uint4 chunks (4 amps, fp16 SoA)
#define PCH    (NCH + NCH / 8)      // 4608 physical chunks (pad c + c>>3: R11 best)

using f2 = __attribute__((ext_vector_type(2))) float;
__device__ __forceinline__ f2 ff2(float a, float b) { f2 r; r.x = a; r.y = b; return r; }

__device__ __forceinline__ unsigned h2u(__half2 h) { return __builtin_bit_cast(unsigned, h); }
__device__ __forceinline__ __half2 u2h(unsigned u) { return __builtin_bit_cast(__half2, u); }
__device__ __forceinline__ unsigned sw16(unsigned u) { return __builtin_amdgcn_alignbit(u, u, 16); }

// ---- Shear RX in packed fp16 (3 pk-FMA per 2D plane pair; swap-free for amp-bit>=1).
// X[k]=(x_{2k},x_{2k+1}), Y[k]=(y_{2k},y_{2k+1}).  T=(t,t), Sn=(-s,-s),
// t = tan(phi/2) rounded to fp16, s derived from rounded t (map stays a rotation).
template <int K>  // K = amp-bit >> 1, for amp-bit >= 1
__device__ __forceinline__ void rot_k(__half2* X, __half2* Y, __half2 T, __half2 Sn) {
#pragma unroll
  for (int k = 0; k < 16; ++k) {
    if (!(k & K)) {
      const int k1 = k | K;
      const __half2 u1 = __hfma2(T, Y[k1], X[k]);
      const __half2 w1 = __hfma2(Sn, u1, Y[k1]);
      X[k]  = __hfma2(T, w1, u1);
      Y[k1] = w1;
      const __half2 u2 = __hfma2(T, Y[k], X[k1]);
      const __half2 w2 = __hfma2(Sn, u2, Y[k]);
      X[k1] = __hfma2(T, w2, u2);
      Y[k]  = w2;
    }
  }
}
// amp-bit 0 (q13): partner inside the packed register -> half-swaps
__device__ __forceinline__ void rot0(__half2* X, __half2* Y, __half2 T, __half2 Sn) {
#pragma unroll
  for (int k = 0; k < 16; ++k) {
    const __half2 sy = __lowhigh2highlow(Y[k]);
    const __half2 u = __hfma2(T, sy, X[k]);
    const __half2 w = __hfma2(Sn, u, sy);
    X[k] = __hfma2(T, w, u);
    Y[k] = __lowhigh2highlow(w);
  }
}

// CNOT-ring fold: registers in pass-D ownership -> full-chunk scatter writes.
__device__ __forceinline__ void cnot_scatter(char* sb, const int* offD, int P,
                                             const __half2* X, const __half2* Y) {
#pragma unroll
  for (int g = 0; g < 8; ++g) {
    const int k0 = 2 * g;
    const unsigned w0 = __builtin_amdgcn_perm(h2u(X[k0 ^ 12]), h2u(X[k0]), 0x07060100u);
    const unsigned w1 = __builtin_amdgcn_perm(h2u(Y[k0 ^ 12]), h2u(Y[k0]), 0x07060100u);
    const unsigned w2 = __builtin_amdgcn_perm(h2u(X[k0 ^ 13]), h2u(X[k0 ^ 1]), 0x05040302u);
    const unsigned w3 = __builtin_amdgcn_perm(h2u(Y[k0 ^ 13]), h2u(Y[k0 ^ 1]), 0x05040302u);
    const bool rev = ((P ^ (__popc(g) & 1)) != 0);
    const uint4 o = make_uint4(rev ? sw16(w2) : w0, rev ? sw16(w3) : w1,
                               rev ? sw16(w0) : w2, rev ? sw16(w1) : w3);
    *(uint4*)(sb + offD[g]) = o;
  }
}

__global__ __launch_bounds__(BLK)
__attribute__((amdgpu_waves_per_eu(4, 4)))   // VGPR cap 128; exactly 2 blocks/CU
void qsim_kernel(const float* __restrict__ x,
                 const float* __restrict__ params,
                 float* __restrict__ out) {
  __shared__ uint4 lds[PCH];                  // 73728 B state, fp16 SoA chunks, padded
  __shared__ float exc[NQ], exs[NQ];
  __shared__ uint2 gTS[NL * NQ];              // per-gate packed (T=(t,t), Sn=(-s,-s))
  __shared__ float red[8][16];
  char* const sb = (char*)lds;

  const int b = blockIdx.x;
  const int t = threadIdx.x;

  // Layer-0 RX folded into the embedding: RX(theta)RX(x)|0> = RX(x+theta)|0>
  if (t < NQ) {
    const float xv = x[b * NQ + t] + params[t];
    exc[t] = cosf(0.5f * xv); exs[t] = sinf(0.5f * xv);
  }
  if (t >= NQ && t < NL * NQ) {               // gate constants for layers 1..3 only
    float ph = 0.5f * params[t];              // phi in [0, pi]
    if (ph > 1.5707964f) ph -= 3.14159265f;   // range-reduce; global -1 is pure phase
    const float tf = tanf(0.5f * ph);
    const __half th = __float2half_rn(tf);
    const float thf = __half2float(th);
    const float sf = 2.0f * thf / (1.0f + thf * thf);  // consistent with rounded t
    gTS[t] = make_uint2(h2u(__half2half2(th)), h2u(__float2half2_rn(-sf)));
  }
  __syncthreads();

  __half2 X[16], Y[16];                       // 32 amps: SoA x/y planes, fp16 packed

  // ---- per-thread bases (phys chunk = c + (c>>3); layer-invariant)
  char* const pA = sb + 16 * (9 * t);
  char* const pB = sb + 16 * (t & 7) + 1152 * (t >> 3);
  char* const pC = sb + 16 * ((t & 63) + ((t >> 3) & 7) + 576 * (t >> 6));
  char* const pD = sb + 16 * (t + (t >> 3));

  // D CNOT-fold target chunks: MA0 = image of amp bits 2..10 (=t) under ring map
  int MA0 = 0;
  {
    const int Me[9] = {0x2007, 0x200F, 0x201F, 0x203F, 0x207F, 0x20FF, 0x21FF, 0x23FF, 0x27FF};
#pragma unroll
    for (int i = 0; i < 9; ++i) if ((t >> i) & 1) MA0 ^= Me[i];
  }
  int offD[8];
#pragma unroll
  for (int g = 0; g < 8; ++g) {
    const int Mrep = ((g & 1) ? 0x2FFF : 0) ^ ((g & 2) ? 0x3FFF : 0) ^ ((g & 4) ? 0x1FFF : 0);
    const int cT = (MA0 ^ Mrep) >> 2;
    offD[g] = 16 * (cT + (cT >> 3));
  }
  const int P = __popc(t) & 1;

  // ---- embedding (with layer-0 RX folded) directly in pass-D ownership:
  // amp a = 4t + 2048m + l ; bits: l->0,1 ; t->2..10 ; m->11,12,13 ; qubit = 13 - bit
  {
    float pb = 1.0f;
#pragma unroll
    for (int i = 0; i < 9; ++i) pb *= ((t >> i) & 1) ? exs[11 - i] : exc[11 - i];
    const int pct = __popc(t);
#pragma unroll
    for (int m = 0; m < 8; ++m) {
      const float fm = ((m & 1) ? exs[2] : exc[2]) * ((m & 2) ? exs[1] : exc[1]) *
                       ((m & 4) ? exs[0] : exc[0]);
      float xv[4], yv[4];
#pragma unroll
      for (int l = 0; l < 4; ++l) {
        const float fl = ((l & 1) ? exs[13] : exc[13]) * ((l & 2) ? exs[12] : exc[12]);
        const float f = pb * fm * fl;
        const int pc = (pct + __popc(m) + __popc(l)) & 3;
        xv[l] = (pc == 0) ? f : ((pc == 2) ? -f : 0.0f);
        yv[l] = (pc == 1) ? -f : ((pc == 3) ? f : 0.0f);
      }
      X[2 * m]     = __floats2half2_rn(xv[0], xv[1]);
      X[2 * m + 1] = __floats2half2_rn(xv[2], xv[3]);
      Y[2 * m]     = __floats2half2_rn(yv[0], yv[1]);
      Y[2 * m + 1] = __floats2half2_rn(yv[2], yv[3]);
    }
  }
  // layer-0 CNOT ring: scatter the embedded state into LDS (layout = pass-A input)
  cnot_scatter(sb, offD, P, X, Y);
  __syncthreads();

#pragma unroll
  for (int layer = 1; layer < NL; ++layer) {
    __half2 T, Sn;
#define MKST(qi) { const uint2 g_ = gTS[layer * NQ + (qi)]; T = u2h(g_.x); Sn = u2h(g_.y); }

    // ---- pass A: amps 32t+j; rotate q13..q9 (amp bits 0..4)
#pragma unroll
    for (int i = 0; i < 8; ++i) {
      const uint4 u = *(const uint4*)(pA + 16 * i);
      X[2 * i] = u2h(u.x); Y[2 * i] = u2h(u.y);
      X[2 * i + 1] = u2h(u.z); Y[2 * i + 1] = u2h(u.w);
    }
    MKST(13); rot0(X, Y, T, Sn);
    MKST(12); rot_k<1>(X, Y, T, Sn);
    MKST(11); rot_k<2>(X, Y, T, Sn);
    MKST(10); rot_k<4>(X, Y, T, Sn);
    MKST(9);  rot_k<8>(X, Y, T, Sn);
#pragma unroll
    for (int i = 0; i < 8; ++i)
      *(uint4*)(pA + 16 * i) = make_uint4(h2u(X[2 * i]), h2u(Y[2 * i]),
                                          h2u(X[2 * i + 1]), h2u(Y[2 * i + 1]));
    __builtin_amdgcn_wave_barrier();          // A->B exchange is wave-private

    // ---- pass B: free {0,1,5,6,7}; rotate q8,q7,q6
#pragma unroll
    for (int m = 0; m < 8; ++m) {
      const uint4 u = *(const uint4*)(pB + 144 * m);
      X[2 * m] = u2h(u.x); Y[2 * m] = u2h(u.y);
      X[2 * m + 1] = u2h(u.z); Y[2 * m + 1] = u2h(u.w);
    }
    MKST(8); rot_k<2>(X, Y, T, Sn);
    MKST(7); rot_k<4>(X, Y, T, Sn);
    MKST(6); rot_k<8>(X, Y, T, Sn);
#pragma unroll
    for (int m = 0; m < 8; ++m)
      *(uint4*)(pB + 144 * m) = make_uint4(h2u(X[2 * m]), h2u(Y[2 * m]),
                                           h2u(X[2 * m + 1]), h2u(Y[2 * m + 1]));
    __builtin_amdgcn_wave_barrier();          // B->C exchange is wave-private

    // ---- pass C: free {0,1,8,9,10}; rotate q5,q4,q3
#pragma unroll
    for (int m = 0; m < 8; ++m) {
      const uint4 u = *(const uint4*)(pC + 1152 * m);
      X[2 * m] = u2h(u.x); Y[2 * m] = u2h(u.y);
      X[2 * m + 1] = u2h(u.z); Y[2 * m + 1] = u2h(u.w);
    }
    MKST(5); rot_k<2>(X, Y, T, Sn);
    MKST(4); rot_k<4>(X, Y, T, Sn);
    MKST(3); rot_k<8>(X, Y, T, Sn);
#pragma unroll
    for (int m = 0; m < 8; ++m)
      *(uint4*)(pC + 1152 * m) = make_uint4(h2u(X[2 * m]), h2u(Y[2 * m]),
                                            h2u(X[2 * m + 1]), h2u(Y[2 * m + 1]));
    __syncthreads();                          // C->D repartition crosses waves

    // ---- pass D: free {0,1,11,12,13}; rotate q2,q1,q0
#pragma unroll
    for (int m = 0; m < 8; ++m) {
      const uint4 u = *(const uint4*)(pD + 9216 * m);
      X[2 * m] = u2h(u.x); Y[2 * m] = u2h(u.y);
      X[2 * m + 1] = u2h(u.z); Y[2 * m + 1] = u2h(u.w);
    }
    if (layer < NL - 1) __syncthreads();      // WAR: all D reads done before CNOT writes
    MKST(2); rot_k<2>(X, Y, T, Sn);
    MKST(1); rot_k<4>(X, Y, T, Sn);
    MKST(0); rot_k<8>(X, Y, T, Sn);
#undef MKST

    if (layer < NL - 1) {
      cnot_scatter(sb, offD, P, X, Y);        // CNOT ring folded into chunk writes
      __syncthreads();                        // RAW for next layer's pass-A read
    }
  }

  // ---- measurement (final CNOT folded via GF(2) linearity); probs in fp32.
  {
    f2 pp[16];
#pragma unroll
    for (int k = 0; k < 16; ++k) {
      const float xl = __low2float(X[k]), xh = __high2float(X[k]);
      const float yl = __low2float(Y[k]), yh = __high2float(Y[k]);
      pp[k] = ff2(fmaf(xl, xl, yl * yl), fmaf(xh, xh, yh * yh));
    }
#pragma unroll
    for (int st = 0; st < 4; ++st) {
      const int h = 1 << st;
#pragma unroll
      for (int k = 0; k < 16; ++k) {
        if (!(k & h)) {
          const f2 u = pp[k], w = pp[k | h];
          pp[k] = u + w;
          pp[k | h] = u - w;
        }
      }
    }
    float w24 = pp[12].x + pp[12].y;
    float w28 = pp[14].x + pp[14].y;
    float w30 = pp[15].x + pp[15].y;
    float w31 = pp[15].x - pp[15].y;
    float w15 = pp[7].x - pp[7].y;

    const int lane = t & 63;
#pragma unroll
    for (int m = 0; m < 6; ++m) {
      const int h = 1 << m;
      const bool hi = (lane & h) != 0;
      float u;
      u = __shfl_xor(w28, h, 64); w28 = hi ? (u - w28) : (u + w28);
      u = __shfl_xor(w30, h, 64); w30 = hi ? (u - w30) : (u + w30);
      u = __shfl_xor(w31, h, 64); w31 = hi ? (u - w31) : (u + w31);
      u = __shfl_xor(w15, h, 64); w15 = hi ? (u - w15) : (u + w15);
      u = __shfl_xor(w24, h, 64); w24 = u + w24;     // plain sum: only lane 0 used
    }
    const int w = t >> 6;
    const float swv = (__popc(w) & 1) ? -1.0f : 1.0f;
    if (lane == 0) {
      red[w][1] = w24;                                   // q1: +
      red[w][2] = w28;                                   // q2: +
      red[w][3] = ((w >> 2) & 1) ? -w28 : w28;           // q3: (-1)^t10
      red[w][4] = (((w >> 1) ^ (w >> 2)) & 1) ? -w28 : w28;  // q4: t9^t10
      red[w][5] = swv * w28;                             // q5: t8^t9^t10
    } else if (lane == 32) { red[w][6]  = swv * w28; }   // q6:  lane mask 0x20
    else if (lane == 48)   { red[w][7]  = swv * w28; }   // q7:  0x30
    else if (lane == 56)   { red[w][8]  = swv * w28; }   // q8:  0x38
    else if (lane == 60)   { red[w][9]  = swv * w28; }   // q9:  0x3C
    else if (lane == 62)   { red[w][10] = swv * w28; }   // q10: 0x3E
    else if (lane == 63)   { red[w][11] = swv * w28;     // q11: 0x3F
                             red[w][12] = swv * w30;     // q12
                             red[w][13] = swv * w31;     // q13
                             red[w][0]  = swv * w15; }   // q0
    __syncthreads();
    if (t < NQ) {
      float sq = 0.0f;
#pragma unroll
      for (int ww = 0; ww < 8; ++ww) sq += red[ww][t];
      out[b * NQ + t] = sq;
    }
  }
}

extern "C" void kernel_launch(void* const* d_in, const int* in_sizes, int n_in,
                              void* d_out, int out_size, void* d_ws, size_t ws_size,
                              hipStream_t stream) {
  const float* x      = (const float*)d_in[0];
  const float* params = (const float*)d_in[1];
  float* out          = (float*)d_out;
  qsim_kernel<<<BATCH, BLK, 0, stream>>>(x, params, out);
}